// Round 2
// baseline (50.217 us; speedup 1.0000x reference)
//
#include <hip/hip_runtime.h>
#include <stdint.h>

#define EPS 1e-5f
#define T_DIM 16384
#define N_DIM 1024
#define K_DIM 1024

// ---------------- workspace layout (bytes) ----------------
// qx   int8  [16384][1024]  @ 0          (16 MiB)
// qw   int8  [1024][1024]   @ 16777216   (1 MiB)
// dq   f32   [16384]        @ 17825792   (64 KiB)   dq[t] = max(rowmax,EPS)/127
// part f64   [256]          @ 17891328   (2 KiB)
// meanf f32  [1]            @ 17893376

typedef int v4i __attribute__((ext_vector_type(4)));

// ---------- kernel 1: wave-per-row x-quant (blocks 0..4095) + |W| partial
// sums (blocks 4096..4351) ----------
__global__ __launch_bounds__(256) void k_xq_wabs(
    const float* __restrict__ x, const float* __restrict__ w,
    char* __restrict__ qx, float* __restrict__ dq, double* __restrict__ part) {
    const int bid = blockIdx.x;
    const int tid = threadIdx.x;

    if (bid < 4096) {
        // ---- per-row absmax + int8 quantize, one wave per row ----
        const int row  = bid * 4 + (tid >> 6);
        const int lane = tid & 63;
        const float4* xr = (const float4*)(x + (long)row * K_DIM);
        float4 v[4];
#pragma unroll
        for (int i = 0; i < 4; ++i) v[i] = xr[i * 64 + lane];
        float m = 0.0f;
#pragma unroll
        for (int i = 0; i < 4; ++i)
            m = fmaxf(m, fmaxf(fmaxf(fabsf(v[i].x), fabsf(v[i].y)),
                               fmaxf(fabsf(v[i].z), fabsf(v[i].w))));
#pragma unroll
        for (int s = 32; s > 0; s >>= 1) m = fmaxf(m, __shfl_xor(m, s));
        m = fmaxf(m, EPS);                        // jnp.clip(rowmax, EPS)
        if (lane == 0) dq[row] = m * (1.0f / 127.0f);
        const float s = 127.0f / m;               // act_scale
        int* qrow = (int*)(qx + (long)row * K_DIM);
#pragma unroll
        for (int i = 0; i < 4; ++i) {
            float f0 = fminf(fmaxf(rintf(v[i].x * s), -128.f), 127.f);
            float f1 = fminf(fmaxf(rintf(v[i].y * s), -128.f), 127.f);
            float f2 = fminf(fmaxf(rintf(v[i].z * s), -128.f), 127.f);
            float f3 = fminf(fmaxf(rintf(v[i].w * s), -128.f), 127.f);
            int q0 = (int)f0, q1 = (int)f1, q2 = (int)f2, q3 = (int)f3;
            qrow[i * 64 + lane] = (q0 & 255) | ((q1 & 255) << 8) |
                                  ((q2 & 255) << 16) | ((q3 & 255) << 24);
        }
    } else {
        // ---- partial |W| sums, f64, deterministic ----
        const int wb = bid - 4096;               // 0..255
        const int base = wb * 256 + tid;         // over 262144 float4
        const float4* w4 = (const float4*)w;
        double sum = 0.0;
#pragma unroll
        for (int i = 0; i < 4; ++i) {
            float4 v = w4[base + i * 65536];
            sum += (double)fabsf(v.x) + (double)fabsf(v.y) +
                   (double)fabsf(v.z) + (double)fabsf(v.w);
        }
        __shared__ double redd[256];
        redd[tid] = sum;
        __syncthreads();
#pragma unroll
        for (int st = 128; st > 0; st >>= 1) {
            if (tid < st) redd[tid] += redd[tid + st];
            __syncthreads();
        }
        if (tid == 0) part[wb] = redd[0];
    }
}

// ---------- kernel 2: finalize mean (redundant per block, deterministic)
//            + ternary-quantize W ----------
__global__ __launch_bounds__(256) void k_wquant(
    const float* __restrict__ w, char* __restrict__ qw,
    const double* __restrict__ part, float* __restrict__ meanf) {
    const int tid = threadIdx.x;
    __shared__ double red[256];
    red[tid] = part[tid];
    __syncthreads();
#pragma unroll
    for (int st = 128; st > 0; st >>= 1) {
        if (tid < st) red[tid] += red[tid + st];
        __syncthreads();
    }
    const double mean = fmax(red[0] / 1048576.0, (double)EPS);  // clip(mean,EPS)
    if (blockIdx.x == 0 && tid == 0) meanf[0] = (float)mean;
    const double ws = 1.0 / mean;                // w_scale
    const long i = (long)blockIdx.x * 256 + tid; // 262144 float4
    float4 v = ((const float4*)w)[i];
    int q0 = (int)rint((double)v.x * ws);
    int q1 = (int)rint((double)v.y * ws);
    int q2 = (int)rint((double)v.z * ws);
    int q3 = (int)rint((double)v.w * ws);
    q0 = max(-1, min(1, q0)); q1 = max(-1, min(1, q1));
    q2 = max(-1, min(1, q2)); q3 = max(-1, min(1, q3));
    int packed = (q0 & 255) | ((q1 & 255) << 8) | ((q2 & 255) << 16) | ((q3 & 255) << 24);
    ((int*)qw)[i] = packed;
}

// ---------- kernel 3: i8 GEMM, 256x128 tile, BK=64, 8 waves, dbuf LDS ----------
// LDS = 2*(256*64 + 128*64) = 48 KiB/block; __launch_bounds__(512,4) caps
// VGPR at 128 -> 2 blocks/CU co-resident, grid 512 = 2 rounds: one block's
// epilogue stores overlap the other's MFMA loop. Per-K-step per CU: MFMA
// ~1300 cyc vs L2 staging ~860 cyc -> K-loop stays MFMA-bound.
#define BM 256
#define BN 128
#define BK 64

__device__ __forceinline__ void gld_lds16(const void* g, void* l) {
    __builtin_amdgcn_global_load_lds(
        (const __attribute__((address_space(1))) void*)g,
        (__attribute__((address_space(3))) void*)l, 16, 0, 0);
}

__global__ __launch_bounds__(512, 4) void k_gemm(
    const char* __restrict__ qx, const char* __restrict__ qw,
    const float* __restrict__ dq, const float* __restrict__ meanf_p,
    const float* __restrict__ bias, float* __restrict__ out) {
    __shared__ __attribute__((aligned(16))) char As[2][BM * BK];   // 2 x 16 KiB
    __shared__ __attribute__((aligned(16))) char Bs[2][BN * BK];   // 2 x 8 KiB

    const int tid  = threadIdx.x;
    const int lane = tid & 63;
    const int wid  = tid >> 6;
    const int wr   = wid >> 1;          // 4x2 wave grid; wave tile 64x64
    const int wc   = wid & 1;

    // 512 blocks = 64 brow x 8 bcol. XCD-bijective remap (512 % 8 == 0):
    // xcd = bid&7 owns works xcd*64..+63 = 8 consecutive brows x 8 bcols
    // -> 2 MiB qx slab + 1 MiB qw resident per XCD L2.
    const int bid  = blockIdx.x;
    const int work = (bid & 7) * 64 + (bid >> 3);
    const int brow = work >> 3;
    const int bcol = work & 7;
    const long arow0 = (long)brow * BM;
    const int  ncol0 = bcol * BN;

    // staging: A covered by 2 passes of 512 thr x 16 B (16 KiB), B by 1 pass
    // (8 KiB). row = off/64, chunk = (off/16)&3 (4 x 16B chunks per row).
    // Swizzle involution S(row,c) = c ^ (row&3), applied on global source
    // AND on read (rule #21): LDS[row][ch] holds G[row][ch ^ (row&3)].
    int a_row[2], a_src[2], a_off[2];
#pragma unroll
    for (int p = 0; p < 2; ++p) {
        int off = tid * 16 + p * 8192;
        int row = off >> 6;
        int ch  = (off >> 4) & 3;
        a_row[p] = row; a_src[p] = (ch ^ (row & 3)) * 16; a_off[p] = off;
    }
    const int b_off = tid * 16;
    const int b_row = b_off >> 6;
    const int b_src = (((b_off >> 4) & 3) ^ (b_row & 3)) * 16;

#define STAGE(k0_, buf_)                                                      \
    {                                                                         \
        _Pragma("unroll")                                                     \
        for (int p = 0; p < 2; ++p) {                                         \
            const char* gA = qx + ((arow0 + a_row[p]) << 10) + (k0_) + a_src[p]; \
            gld_lds16(gA, As[buf_] + a_off[p]);                              \
        }                                                                     \
        const char* gB = qw + (((long)(ncol0 + b_row)) << 10) + (k0_) + b_src; \
        gld_lds16(gB, Bs[buf_] + b_off);                                     \
    }

    v4i acc[4][4] = {};

    const int r15 = lane & 15;
    const int cg  = lane >> 4;          // k-chunk group 0..3
    // read rows are base(mult of 16) + r15 -> row&3 == r15&3
    const int rch = ((cg ^ (r15 & 3)) & 3) * 16;   // swizzled byte chunk

    STAGE(0, 0);
    __syncthreads();

#pragma unroll
    for (int k0 = 0; k0 < 16; ++k0) {            // K-steps of 64
        const int cur = k0 & 1;
        if (k0 < 15) STAGE((k0 + 1) * BK, cur ^ 1);   // prefetch next tile

        v4i a[4], b[4];
#pragma unroll
        for (int m = 0; m < 4; ++m) {
            int row = wr * 64 + m * 16 + r15;
            a[m] = *(const v4i*)(As[cur] + row * BK + rch);
        }
#pragma unroll
        for (int n = 0; n < 4; ++n) {
            int row = wc * 64 + n * 16 + r15;
            b[n] = *(const v4i*)(Bs[cur] + row * BK + rch);
        }
#pragma unroll
        for (int m = 0; m < 4; ++m)
#pragma unroll
            for (int n = 0; n < 4; ++n)
                acc[m][n] = __builtin_amdgcn_mfma_i32_16x16x64_i8(
                    a[m], b[n], acc[m][n], 0, 0, 0);

        __syncthreads();   // one barrier per K-step; co-resident second block
                           // covers the vmcnt drain
    }

    // epilogue: C/D layout col=lane&15, row=(lane>>4)*4+reg
    const float wmean = meanf_p[0];
    const int ocol = ncol0 + wc * 64 + r15;
    float bv[4];
#pragma unroll
    for (int n = 0; n < 4; ++n) bv[n] = bias[ocol + n * 16];
#pragma unroll
    for (int m = 0; m < 4; ++m) {
#pragma unroll
        for (int rr = 0; rr < 4; ++rr) {
            long orow = arow0 + wr * 64 + m * 16 + cg * 4 + rr;
            float d = dq[orow] * wmean;
#pragma unroll
            for (int n = 0; n < 4; ++n)
                out[orow * N_DIM + ocol + n * 16] = (float)acc[m][n][rr] * d + bv[n];
        }
    }
}

extern "C" void kernel_launch(void* const* d_in, const int* in_sizes, int n_in,
                              void* d_out, int out_size, void* d_ws, size_t ws_size,
                              hipStream_t stream) {
    (void)in_sizes; (void)n_in; (void)out_size; (void)ws_size;
    const float* x    = (const float*)d_in[0];
    const float* w    = (const float*)d_in[1];
    const float* bias = (const float*)d_in[2];
    float* out = (float*)d_out;

    char*   ws    = (char*)d_ws;
    char*   qx    = ws;
    char*   qw    = ws + 16777216;
    float*  dq    = (float*)(ws + 17825792);
    double* part  = (double*)(ws + 17891328);
    float*  meanf = (float*)(ws + 17893376);

    k_xq_wabs<<<dim3(4096 + 256), dim3(256), 0, stream>>>(x, w, qx, dq, part);
    k_wquant <<<dim3(1024),       dim3(256), 0, stream>>>(w, qw, part, meanf);
    k_gemm   <<<dim3(512),        dim3(512), 0, stream>>>(qx, qw, dq, meanf, bias, out);
}

// Round 3
// 47.502 us; speedup vs baseline: 1.0571x; 1.0571x over previous
//
#include <hip/hip_runtime.h>
#include <stdint.h>

#define EPS 1e-5f
#define T_DIM 16384
#define N_DIM 1024
#define K_DIM 1024

// ---------------- workspace layout (bytes) ----------------
// qx   int8  [16384][1024]  @ 0          (16 MiB)
// qw   int8  [1024][1024]   @ 16777216   (1 MiB)
// dq   f32   [16384]        @ 17825792   (64 KiB)   dq[t] = max(rowmax,EPS)/127
// part f64   [256]          @ 17891328   (2 KiB)
// meanf f32  [1]            @ 17893376

typedef int v4i  __attribute__((ext_vector_type(4)));
typedef int v16i __attribute__((ext_vector_type(16)));

// ---------- kernel 1: wave-per-row x-quant (blocks 0..4095) + |W| partial
// sums (blocks 4096..4351) ----------
__global__ __launch_bounds__(256) void k_xq_wabs(
    const float* __restrict__ x, const float* __restrict__ w,
    char* __restrict__ qx, float* __restrict__ dq, double* __restrict__ part) {
    const int bid = blockIdx.x;
    const int tid = threadIdx.x;

    if (bid < 4096) {
        // ---- per-row absmax + int8 quantize, one wave per row ----
        const int row  = bid * 4 + (tid >> 6);
        const int lane = tid & 63;
        const float4* xr = (const float4*)(x + (long)row * K_DIM);
        float4 v[4];
#pragma unroll
        for (int i = 0; i < 4; ++i) v[i] = xr[i * 64 + lane];
        float m = 0.0f;
#pragma unroll
        for (int i = 0; i < 4; ++i)
            m = fmaxf(m, fmaxf(fmaxf(fabsf(v[i].x), fabsf(v[i].y)),
                               fmaxf(fabsf(v[i].z), fabsf(v[i].w))));
#pragma unroll
        for (int s = 32; s > 0; s >>= 1) m = fmaxf(m, __shfl_xor(m, s));
        m = fmaxf(m, EPS);                        // jnp.clip(rowmax, EPS)
        if (lane == 0) dq[row] = m * (1.0f / 127.0f);
        const float s = 127.0f / m;               // act_scale
        int* qrow = (int*)(qx + (long)row * K_DIM);
#pragma unroll
        for (int i = 0; i < 4; ++i) {
            float f0 = fminf(fmaxf(rintf(v[i].x * s), -128.f), 127.f);
            float f1 = fminf(fmaxf(rintf(v[i].y * s), -128.f), 127.f);
            float f2 = fminf(fmaxf(rintf(v[i].z * s), -128.f), 127.f);
            float f3 = fminf(fmaxf(rintf(v[i].w * s), -128.f), 127.f);
            int q0 = (int)f0, q1 = (int)f1, q2 = (int)f2, q3 = (int)f3;
            qrow[i * 64 + lane] = (q0 & 255) | ((q1 & 255) << 8) |
                                  ((q2 & 255) << 16) | ((q3 & 255) << 24);
        }
    } else {
        // ---- partial |W| sums, f64, deterministic ----
        const int wb = bid - 4096;               // 0..255
        const int base = wb * 256 + tid;         // over 262144 float4
        const float4* w4 = (const float4*)w;
        double sum = 0.0;
#pragma unroll
        for (int i = 0; i < 4; ++i) {
            float4 v = w4[base + i * 65536];
            sum += (double)fabsf(v.x) + (double)fabsf(v.y) +
                   (double)fabsf(v.z) + (double)fabsf(v.w);
        }
        __shared__ double redd[256];
        redd[tid] = sum;
        __syncthreads();
#pragma unroll
        for (int st = 128; st > 0; st >>= 1) {
            if (tid < st) redd[tid] += redd[tid + st];
            __syncthreads();
        }
        if (tid == 0) part[wb] = redd[0];
    }
}

// ---------- kernel 2: finalize mean (redundant per block, deterministic)
//            + ternary-quantize W ----------
__global__ __launch_bounds__(256) void k_wquant(
    const float* __restrict__ w, char* __restrict__ qw,
    const double* __restrict__ part, float* __restrict__ meanf) {
    const int tid = threadIdx.x;
    __shared__ double red[256];
    red[tid] = part[tid];
    __syncthreads();
#pragma unroll
    for (int st = 128; st > 0; st >>= 1) {
        if (tid < st) red[tid] += red[tid + st];
        __syncthreads();
    }
    const double mean = fmax(red[0] / 1048576.0, (double)EPS);  // clip(mean,EPS)
    if (blockIdx.x == 0 && tid == 0) meanf[0] = (float)mean;
    const double ws = 1.0 / mean;                // w_scale
    const long i = (long)blockIdx.x * 256 + tid; // 262144 float4
    float4 v = ((const float4*)w)[i];
    int q0 = (int)rint((double)v.x * ws);
    int q1 = (int)rint((double)v.y * ws);
    int q2 = (int)rint((double)v.z * ws);
    int q3 = (int)rint((double)v.w * ws);
    q0 = max(-1, min(1, q0)); q1 = max(-1, min(1, q1));
    q2 = max(-1, min(1, q2)); q3 = max(-1, min(1, q3));
    int packed = (q0 & 255) | ((q1 & 255) << 8) | ((q2 & 255) << 16) | ((q3 & 255) << 24);
    ((int*)qw)[i] = packed;
}

// ---------- kernel 3: i8 GEMM, 256x256 tile, BK=128, 8 waves, dbuf LDS ----------
// R0 structure (best measured) with 32x32x32 i8 MFMA (4404 vs 3944 TOPS).
// K-loop per SIMD per K-step: MFMA ~2340 cyc vs L2 staging ~1170 -> MFMA-bound.
#define BM 256
#define BN 256
#define BK 128

__device__ __forceinline__ void gld_lds16(const void* g, void* l) {
    __builtin_amdgcn_global_load_lds(
        (const __attribute__((address_space(1))) void*)g,
        (__attribute__((address_space(3))) void*)l, 16, 0, 0);
}

__global__ __launch_bounds__(512, 2) void k_gemm(
    const char* __restrict__ qx, const char* __restrict__ qw,
    const float* __restrict__ dq, const float* __restrict__ meanf_p,
    const float* __restrict__ bias, float* __restrict__ out) {
    __shared__ __attribute__((aligned(16))) char As[2][BM * BK];   // 2 x 32 KiB
    __shared__ __attribute__((aligned(16))) char Bs[2][BN * BK];   // 2 x 32 KiB

    const int tid  = threadIdx.x;
    const int lane = tid & 63;
    const int wid  = tid >> 6;
    const int wr   = wid >> 2;          // 2x4 wave grid; wave tile 128x64
    const int wc   = wid & 3;

    // 256 blocks = 64 brow x 4 bcol. XCD-bijective remap: xcd = bid&7 owns
    // works xcd*32..+31 = 8 consecutive brows x 4 bcols -> 2 MiB qx slab +
    // 1 MiB qw resident per XCD L2.
    const int bid  = blockIdx.x;
    const int work = (bid & 7) * 32 + (bid >> 3);
    const int brow = work >> 2;
    const int bcol = work & 3;
    const long arow0 = (long)brow * BM;
    const int  ncol0 = bcol * BN;

    // staging: thread covers LDS linear offsets tid*16 + p*8192, p=0..3
    // (32 KiB per matrix per buffer). row = off/128, chunk = (off/16)&7.
    // Swizzle involution S(row,c) = c ^ (row&7), applied on global source
    // AND on read (rule #21): LDS[row][ch] holds G[row][ch ^ (row&7)].
    int s_row[4], s_src[4], s_off[4];
#pragma unroll
    for (int p = 0; p < 4; ++p) {
        int off = tid * 16 + p * 8192;
        int row = off >> 7;
        int ch  = (off >> 4) & 7;
        int sch = ch ^ (row & 7);
        s_row[p] = row; s_src[p] = sch * 16; s_off[p] = off;
    }

#define STAGE(k0_, buf_)                                                      \
    {                                                                         \
        _Pragma("unroll")                                                     \
        for (int p = 0; p < 4; ++p) {                                         \
            const char* gA = qx + ((arow0 + s_row[p]) << 10) + (k0_) + s_src[p]; \
            gld_lds16(gA, As[buf_] + s_off[p]);                               \
            const char* gB = qw + (((long)(ncol0 + s_row[p])) << 10) + (k0_) + s_src[p]; \
            gld_lds16(gB, Bs[buf_] + s_off[p]);                               \
        }                                                                     \
    }

    // wave tile 128x64 = 4x2 of 32x32; acc 16 i32/lane each
    v16i acc[4][2] = {};

    const int r31  = lane & 31;
    const int half = lane >> 5;         // which 16B half of the 32B k-slice
    const int sw   = lane & 7;          // read-side swizzle (row&7 == lane&7)

    STAGE(0, 0);
    __syncthreads();

#pragma unroll
    for (int k0 = 0; k0 < 8; ++k0) {             // K-steps of 128
        const int cur = k0 & 1;
        if (k0 < 7) STAGE((k0 + 1) * BK, cur ^ 1);    // prefetch next tile

#pragma unroll
        for (int kk = 0; kk < 4; ++kk) {         // four 32-wide k-slices
            const int c = kk * 2 + half;         // global 16B-chunk index 0..7
            const int rch = (c ^ sw) * 16;       // swizzled byte chunk in row
            v4i a[4], b[2];
#pragma unroll
            for (int m = 0; m < 4; ++m) {
                int row = wr * 128 + m * 32 + r31;
                a[m] = *(const v4i*)(As[cur] + row * BK + rch);
            }
#pragma unroll
            for (int n = 0; n < 2; ++n) {
                int row = wc * 64 + n * 32 + r31;
                b[n] = *(const v4i*)(Bs[cur] + row * BK + rch);
            }
#pragma unroll
            for (int m = 0; m < 4; ++m)
#pragma unroll
                for (int n = 0; n < 2; ++n)
                    acc[m][n] = __builtin_amdgcn_mfma_i32_32x32x32_i8(
                        a[m], b[n], acc[m][n], 0, 0, 0);
        }
        __syncthreads();   // one barrier per K-step; 32 MFMA/wave cover the
                           // L2-resident staging latency before the drain
    }

    // epilogue: 32x32 C/D layout col=lane&31, row=(reg&3)+8*(reg>>2)+4*(lane>>5)
    const float wmean = meanf_p[0];
    const int ocol = ncol0 + wc * 64 + r31;
    const float bv0 = bias[ocol];
    const float bv1 = bias[ocol + 32];
#pragma unroll
    for (int m = 0; m < 4; ++m) {
#pragma unroll
        for (int rg = 0; rg < 4; ++rg) {         // reg>>2
#pragma unroll
            for (int rq = 0; rq < 4; ++rq) {     // reg&3
                const int r = rg * 4 + rq;
                const long orow = arow0 + wr * 128 + m * 32 + rq + rg * 8 + half * 4;
                const float d = dq[orow] * wmean;
                out[orow * N_DIM + ocol]      = (float)acc[m][0][r] * d + bv0;
                out[orow * N_DIM + ocol + 32] = (float)acc[m][1][r] * d + bv1;
            }
        }
    }
}

extern "C" void kernel_launch(void* const* d_in, const int* in_sizes, int n_in,
                              void* d_out, int out_size, void* d_ws, size_t ws_size,
                              hipStream_t stream) {
    (void)in_sizes; (void)n_in; (void)out_size; (void)ws_size;
    const float* x    = (const float*)d_in[0];
    const float* w    = (const float*)d_in[1];
    const float* bias = (const float*)d_in[2];
    float* out = (float*)d_out;

    char*   ws    = (char*)d_ws;
    char*   qx    = ws;
    char*   qw    = ws + 16777216;
    float*  dq    = (float*)(ws + 17825792);
    double* part  = (double*)(ws + 17891328);
    float*  meanf = (float*)(ws + 17893376);

    k_xq_wabs<<<dim3(4096 + 256), dim3(256), 0, stream>>>(x, w, qx, dq, part);
    k_wquant <<<dim3(1024),       dim3(256), 0, stream>>>(w, qw, part, meanf);
    k_gemm   <<<dim3(256),        dim3(512), 0, stream>>>(qx, qw, dq, meanf, bias, out);
}